// Round 2
// baseline (617.384 us; speedup 1.0000x reference)
//
#include <hip/hip_runtime.h>
#include <hip/hip_bf16.h>
#include <stdint.h>

#define SCALE_ 0.125f

typedef __bf16 bf16x8 __attribute__((ext_vector_type(8)));
typedef float f32x4 __attribute__((ext_vector_type(4)));
typedef unsigned short us8v __attribute__((ext_vector_type(8)));

__device__ __forceinline__ unsigned short f2bf(float f) {
  unsigned int u = __builtin_bit_cast(unsigned int, f);
  u += 0x7fffu + ((u >> 16) & 1u);
  return (unsigned short)(u >> 16);
}
__device__ __forceinline__ float bf2f(unsigned short h) {
  unsigned int u = ((unsigned int)h) << 16;
  return __builtin_bit_cast(float, u);
}
__device__ __forceinline__ f32x4 mfma16(bf16x8 a, bf16x8 b, f32x4 c) {
  return __builtin_amdgcn_mfma_f32_16x16x32_bf16(a, b, c, 0, 0, 0);
}
// async global->LDS, 16B per lane. LDS dest must be wave-uniform base + lane*16.
__device__ __forceinline__ void gl2lds16(const unsigned short* g, unsigned short* l) {
  __builtin_amdgcn_global_load_lds(
      (const __attribute__((address_space(1))) unsigned int*)g,
      (__attribute__((address_space(3))) unsigned int*)l, 16, 0, 0);
}

// ---------------- fp32 -> bf16 convert ----------------
__global__ __launch_bounds__(256) void cvt_kernel(const float* __restrict__ src,
                                                  unsigned short* __restrict__ dst,
                                                  int n8) {
  int i = blockIdx.x * 256 + threadIdx.x;
  if (i >= n8) return;
  us8v o;
#pragma unroll
  for (int e = 0; e < 8; ++e) o[e] = f2bf(src[(size_t)i * 8 + e]);
  *(us8v*)(dst + (size_t)i * 8) = o;
}

// ---------------- GEMM: C = A(Mx1024) @ W^T, W is (1024x1024) row-major ----------------
// m97 structure: 128x128 tile, BK=32, global_load_lds(16B) staging, 2 barriers/K-step.
// MODE 0: z selects Wq/Wk/Wv; epilogue RoPE (z<2) and write (B,H,S,D) bf16.
// MODE 1: plain fp32 store to Out (o_proj).
template <int MODE>
__global__ __launch_bounds__(256, 2) void gemm_kernel(
    const unsigned short* __restrict__ A, const unsigned short* __restrict__ W0,
    const unsigned short* __restrict__ W1, const unsigned short* __restrict__ W2,
    unsigned short* __restrict__ Qb, unsigned short* __restrict__ Kb,
    unsigned short* __restrict__ Vb, const float* __restrict__ cosT,
    const float* __restrict__ sinT, float* __restrict__ Out) {
  __shared__ unsigned short As[128 * 32];
  __shared__ unsigned short Bs[128 * 32];
  const int tid = threadIdx.x;
  const int lane = tid & 63, wv = tid >> 6;
  const int lr = lane & 15, lg = lane >> 4;
  const int wr = wv >> 1, wc = wv & 1;
  const int tm = blockIdx.y, tn = blockIdx.x;
  const int z = blockIdx.z;
  const unsigned short* Wp = (MODE == 1) ? W0 : (z == 0 ? W0 : (z == 1 ? W1 : W2));
  const unsigned short* Ab = A + (size_t)tm * 128 * 1024;
  const unsigned short* Wb = Wp + (size_t)tn * 128 * 1024;

  const int srow = tid >> 2;        // 0..63 (round 0), +64 (round 1)
  const int scol = (tid & 3) * 8;   // 0,8,16,24 within 32-K tile

  f32x4 zero = {0.f, 0.f, 0.f, 0.f};
  f32x4 acc[4][4];
#pragma unroll
  for (int i = 0; i < 4; ++i)
#pragma unroll
    for (int j = 0; j < 4; ++j) acc[i][j] = zero;

  for (int ks = 0; ks < 32; ++ks) {
    const int k0 = ks * 32;
    __syncthreads();  // previous compute done, LDS free
    gl2lds16(Ab + (size_t)srow * 1024 + k0 + scol, As + srow * 32 + scol);
    gl2lds16(Ab + (size_t)(64 + srow) * 1024 + k0 + scol, As + (64 + srow) * 32 + scol);
    gl2lds16(Wb + (size_t)srow * 1024 + k0 + scol, Bs + srow * 32 + scol);
    gl2lds16(Wb + (size_t)(64 + srow) * 1024 + k0 + scol, Bs + (64 + srow) * 32 + scol);
    __syncthreads();  // (compiler drains vmcnt before barrier) LDS ready
    bf16x8 av[4], bv[4];
#pragma unroll
    for (int mt = 0; mt < 4; ++mt)
      av[mt] = *(const bf16x8*)(As + (wr * 64 + mt * 16 + lr) * 32 + lg * 8);
#pragma unroll
    for (int nt = 0; nt < 4; ++nt)
      bv[nt] = *(const bf16x8*)(Bs + (wc * 64 + nt * 16 + lr) * 32 + lg * 8);
    __builtin_amdgcn_s_setprio(1);
#pragma unroll
    for (int mt = 0; mt < 4; ++mt)
#pragma unroll
      for (int nt = 0; nt < 4; ++nt)
        acc[mt][nt] = mfma16(av[mt], bv[nt], acc[mt][nt]);
    __builtin_amdgcn_s_setprio(0);
  }

  if constexpr (MODE == 0) {
    unsigned short* Dst = (z == 0) ? Qb : (z == 1 ? Kb : Vb);
#pragma unroll
    for (int mt = 0; mt < 4; ++mt) {
#pragma unroll
      for (int r = 0; r < 4; ++r) {
        const int m = tm * 128 + wr * 64 + mt * 16 + lg * 4 + r;
        const int b = m >> 12, s = m & 4095;
#pragma unroll
        for (int nt = 0; nt < 4; ++nt) {
          const int n = tn * 128 + wc * 64 + nt * 16 + lr;
          const int h = n >> 6, d = n & 63;
          float v = acc[mt][nt][r];
          if (z < 2) {  // RoPE
            const float cs = cosT[s * 64 + d];
            const float sn = sinT[s * 64 + d];
            const float pv = acc[mt][nt ^ 2][r];
            v = v * cs + ((nt < 2) ? -pv : pv) * sn;
          }
          Dst[((size_t)(b * 16 + h) * 4096 + s) * 64 + d] = f2bf(v);
        }
      }
    }
  } else {
#pragma unroll
    for (int mt = 0; mt < 4; ++mt) {
#pragma unroll
      for (int r = 0; r < 4; ++r) {
        const int m = tm * 128 + wr * 64 + mt * 16 + lg * 4 + r;
#pragma unroll
        for (int nt = 0; nt < 4; ++nt) {
          const int n = tn * 128 + wc * 64 + nt * 16 + lr;
          Out[(size_t)m * 1024 + n] = acc[mt][nt][r];
        }
      }
    }
  }
}

// ---------------- RFA prep: beta/gamma softmax over 128 chunk positions ----------------
__global__ __launch_bounds__(128) void prep_kernel(
    const unsigned short* __restrict__ Kb, const unsigned short* __restrict__ Vb,
    const float* __restrict__ mu, const float* __restrict__ phi,
    unsigned short* __restrict__ rfaK, unsigned short* __restrict__ rfaV) {
  __shared__ float kc[128][65];
  __shared__ float betaS[128], gammaS[128];
  __shared__ float red[8];
  const int tid = threadIdx.x, lane = tid & 63, wid = tid >> 6;
  const int bh = blockIdx.x >> 5, c = blockIdx.x & 31;
  const int h = bh & 15;
  const size_t rowbase = ((size_t)bh * 4096 + c * 128 + tid) * 64;

  float nn = 0.f, dmu = 0.f, dphi = 0.f;
#pragma unroll
  for (int d8 = 0; d8 < 8; ++d8) {
    us8v kv = *(const us8v*)(Kb + rowbase + d8 * 8);
#pragma unroll
    for (int e = 0; e < 8; ++e) {
      const int d = d8 * 8 + e;
      const float kf = bf2f(kv[e]);
      kc[tid][d] = kf;
      nn += kf * kf;
      dmu += kf * mu[h * 64 + d];
      dphi += kf * phi[h * 64 + d];
    }
  }
  const float lb = SCALE_ * dmu - 0.5f * SCALE_ * nn;
  const float lgm = SCALE_ * dphi - 0.5f * SCALE_ * nn;
  float mb = lb, mg = lgm;
  for (int off = 1; off < 64; off <<= 1) {
    mb = fmaxf(mb, __shfl_xor(mb, off));
    mg = fmaxf(mg, __shfl_xor(mg, off));
  }
  if (lane == 0) { red[wid * 2] = mb; red[wid * 2 + 1] = mg; }
  __syncthreads();
  mb = fmaxf(red[0], red[2]);
  mg = fmaxf(red[1], red[3]);
  const float eb = __expf(lb - mb), eg = __expf(lgm - mg);
  float sb = eb, sg = eg;
  for (int off = 1; off < 64; off <<= 1) {
    sb += __shfl_xor(sb, off);
    sg += __shfl_xor(sg, off);
  }
  if (lane == 0) { red[4 + wid * 2] = sb; red[4 + wid * 2 + 1] = sg; }
  betaS[tid] = eb;
  gammaS[tid] = eg;
  __syncthreads();
  sb = red[4] + red[6];
  sg = red[5] + red[7];

  if (tid < 64) {
    float a = 0.f;
    for (int j = 0; j < 128; ++j) a += betaS[j] * kc[j][tid];
    rfaK[((size_t)bh * 32 + c) * 64 + tid] = f2bf(a / sb);
  }
  __syncthreads();
#pragma unroll
  for (int d8 = 0; d8 < 8; ++d8) {
    us8v vv = *(const us8v*)(Vb + rowbase + d8 * 8);
#pragma unroll
    for (int e = 0; e < 8; ++e) kc[tid][d8 * 8 + e] = bf2f(vv[e]);
  }
  __syncthreads();
  if (tid < 64) {
    float a = 0.f;
    for (int j = 0; j < 128; ++j) a += gammaS[j] * kc[j][tid];
    rfaV[((size_t)bh * 32 + c) * 64 + tid] = f2bf(a / sg);
  }
}

// ---------------- attention tile body ----------------
// LDS layouts are XOR-swizzled: Vt[d][j ^ (d&56)], Pl[row][col ^ ((row&7)<<3)].
// The XOR only touches bits>=3 of the column; b128 reads start 8-aligned so
// they stay contiguous and 16B-aligned, while the scalar transpose-writes
// spread across all 32 banks (was a 16-way conflict).
template <int NCT, bool CH>
__device__ __forceinline__ void attn_tile(
    const unsigned short* __restrict__ ksrc, int t, int w, int qrow_w, int lr,
    int lg, int vd0, int vjb, const bf16x8* qa, f32x4* o, float* m_run,
    float* l_run, us8v* vreg, const unsigned short* __restrict__ vnext, int nnext,
    unsigned short (*__restrict__ PlW)[136], unsigned short (*__restrict__ VtP)[136]) {
  // --- QK^T (K read direct from global; V for this tile already in vreg) ---
  f32x4 st[NCT];
#pragma unroll
  for (int ct = 0; ct < NCT; ++ct) {
    bf16x8 b0 = *(const bf16x8*)(ksrc + (ct * 16 + lr) * 64 + lg * 8);
    bf16x8 b1 = *(const bf16x8*)(ksrc + (ct * 16 + lr) * 64 + 32 + lg * 8);
    f32x4 sa = {0.f, 0.f, 0.f, 0.f};
    sa = mfma16(qa[0], b0, sa);
    sa = mfma16(qa[1], b1, sa);
#pragma unroll
    for (int r = 0; r < 4; ++r) {
      float sv = sa[r] * SCALE_;
      if (!CH) {
        const int jcol = t * 128 + ct * 16 + lr;
        const int qr = qrow_w + lg * 4 + r;
        if (jcol > qr) sv = -1e30f;
      } else {
        const int cidx = ct * 16 + lr;
        if (cidx >= 4 * w) sv = -1e30f;
      }
      sa[r] = sv;
    }
    st[ct] = sa;
  }
  // --- online softmax ---
  float al[4];
#pragma unroll
  for (int r = 0; r < 4; ++r) {
    float rm = st[0][r];
#pragma unroll
    for (int ct = 1; ct < NCT; ++ct) rm = fmaxf(rm, st[ct][r]);
    rm = fmaxf(rm, __shfl_xor(rm, 1));
    rm = fmaxf(rm, __shfl_xor(rm, 2));
    rm = fmaxf(rm, __shfl_xor(rm, 4));
    rm = fmaxf(rm, __shfl_xor(rm, 8));
    const float mn = fmaxf(m_run[r], rm);
    const float a = __expf(m_run[r] - mn);
    float rs = 0.f;
#pragma unroll
    for (int ct = 0; ct < NCT; ++ct) {
      const float p = __expf(st[ct][r] - mn);
      st[ct][r] = p;
      rs += p;
    }
    rs += __shfl_xor(rs, 1);
    rs += __shfl_xor(rs, 2);
    rs += __shfl_xor(rs, 4);
    rs += __shfl_xor(rs, 8);
    l_run[r] = l_run[r] * a + rs;
    m_run[r] = mn;
    al[r] = a;
  }
#pragma unroll
  for (int dt = 0; dt < 4; ++dt)
#pragma unroll
    for (int r = 0; r < 4; ++r) o[dt][r] *= al[r];
  // P -> LDS (wave-private buffer; barrier below is for Vt, not Pl)
#pragma unroll
  for (int ct = 0; ct < NCT; ++ct)
#pragma unroll
    for (int r = 0; r < 4; ++r) {
      const int row = lg * 4 + r;
      PlW[row][(ct * 16 + lr) ^ ((row & 7) << 3)] = f2bf(st[ct][r]);
    }
  __syncthreads();  // prev tile's PV reads of Vt are done
  // --- stage V^T from prefetched regs (swizzled scalar writes, ~conflict-free) ---
  if (!CH) {
#pragma unroll
    for (int i = 0; i < 4; ++i) {
      const int j = i * 32 + vjb;
#pragma unroll
      for (int e = 0; e < 8; ++e) VtP[vd0 + e][j ^ vd0] = vreg[i][e];
    }
  } else {
#pragma unroll
    for (int e = 0; e < 8; ++e) VtP[vd0 + e][vjb ^ vd0] = vreg[0][e];
  }
  // --- prefetch next tile's V (latency hides under next QK^T + this PV) ---
  if (nnext) {
    vreg[0] = *(const us8v*)(vnext);
    if (nnext == 4) {
#pragma unroll
      for (int i = 1; i < 4; ++i) vreg[i] = *(const us8v*)(vnext + (size_t)i * 32 * 64);
    }
  }
  __syncthreads();  // Vt ready
  // --- PV ---
  constexpr int NKS = CH ? 1 : 4;
  __builtin_amdgcn_s_setprio(1);
#pragma unroll
  for (int ks = 0; ks < NKS; ++ks) {
    bf16x8 pa = *(const bf16x8*)(&PlW[lr][(ks * 32 + lg * 8) ^ ((lr & 7) << 3)]);
#pragma unroll
    for (int dt = 0; dt < 4; ++dt) {
      const int d = dt * 16 + lr;
      bf16x8 vb = *(const bf16x8*)(&VtP[d][(ks * 32 + lg * 8) ^ (d & 56)]);
      o[dt] = mfma16(pa, vb, o[dt]);
    }
  }
  __builtin_amdgcn_s_setprio(0);
}

__global__ __launch_bounds__(256, 4) void attn_kernel(
    const unsigned short* __restrict__ Qb, const unsigned short* __restrict__ Kb,
    const unsigned short* __restrict__ Vb, const unsigned short* __restrict__ rfaK,
    const unsigned short* __restrict__ rfaV, unsigned short* __restrict__ AO) {
  __shared__ unsigned short Vt[64][136];
  __shared__ unsigned short Pl[4][16][136];
  const int tid = threadIdx.x, lane = tid & 63, wv = tid >> 6;
  const int lr = lane & 15, lg = lane >> 4;
  const int qt = blockIdx.x & 7, w = (blockIdx.x >> 3) & 7, bh = blockIdx.x >> 6;
  const size_t headbase = (size_t)bh * 4096 * 64;
  const int qrow_w = qt * 64 + wv * 16;

  bf16x8 qa[2];
  {
    const size_t qoff = headbase + (size_t)(w * 512 + qrow_w + lr) * 64;
    qa[0] = *(const bf16x8*)(Qb + qoff + lg * 8);
    qa[1] = *(const bf16x8*)(Qb + qoff + 32 + lg * 8);
  }
  f32x4 o[4];
  float m_run[4], l_run[4];
  {
    f32x4 zero = {0.f, 0.f, 0.f, 0.f};
#pragma unroll
    for (int dt = 0; dt < 4; ++dt) o[dt] = zero;
#pragma unroll
    for (int r = 0; r < 4; ++r) { m_run[r] = -INFINITY; l_run[r] = 0.f; }
  }

  const int nkt = (qt + 2) >> 1;               // window k-tiles of 128
  const int ntiles = nkt + ((w > 0) ? 1 : 0);  // + chunk tile
  const int vd0 = (tid & 7) * 8;               // d-base staged by this thread
  const int vjb = tid >> 3;                    // j index staged by this thread

  us8v vreg[4];
  {  // prefetch V for tile 0 (always a window tile)
    const unsigned short* vsrc = Vb + headbase + (size_t)(w * 512) * 64;
#pragma unroll
    for (int i = 0; i < 4; ++i)
      vreg[i] = *(const us8v*)(vsrc + (size_t)(i * 32 + vjb) * 64 + vd0);
  }

  for (int t = 0; t < ntiles; ++t) {
    const bool ischunk = (t == nkt);
    // next-tile V prefetch source
    int nnext = 0;
    const unsigned short* vnext = nullptr;
    if (t + 1 < ntiles) {
      if (t + 1 == nkt) {
        nnext = 1;
        vnext = rfaV + ((size_t)bh * 32 + vjb) * 64 + vd0;
      } else {
        nnext = 4;
        vnext = Vb + headbase + (size_t)(w * 512 + (t + 1) * 128 + vjb) * 64 + vd0;
      }
    }
    if (!ischunk) {
      attn_tile<8, false>(Kb + headbase + (size_t)(w * 512 + t * 128) * 64, t, w,
                          qrow_w, lr, lg, vd0, vjb, qa, o, m_run, l_run, vreg,
                          vnext, nnext, Pl[wv], Vt);
    } else {
      attn_tile<2, true>(rfaK + (size_t)bh * 32 * 64, t, w, qrow_w, lr, lg, vd0,
                         vjb, qa, o, m_run, l_run, vreg, vnext, nnext, Pl[wv], Vt);
    }
  }
  const int b = bh >> 4, h = bh & 15;
#pragma unroll
  for (int r = 0; r < 4; ++r) {
    const float inv = 1.0f / l_run[r];
    const int s = w * 512 + qrow_w + lg * 4 + r;
#pragma unroll
    for (int dt = 0; dt < 4; ++dt) {
      AO[((size_t)(b * 4096 + s)) * 1024 + h * 64 + dt * 16 + lr] =
          f2bf(o[dt][r] * inv);
    }
  }
}

// ---------------- host launch ----------------
extern "C" void kernel_launch(void* const* d_in, const int* in_sizes, int n_in,
                              void* d_out, int out_size, void* d_ws, size_t ws_size,
                              hipStream_t stream) {
  const float* hidden = (const float*)d_in[0];
  const float* Wq = (const float*)d_in[1];
  const float* Wk = (const float*)d_in[2];
  const float* Wv = (const float*)d_in[3];
  const float* Wo = (const float*)d_in[4];
  const float* mu = (const float*)d_in[5];
  const float* phi = (const float*)d_in[6];
  const float* cosT = (const float*)d_in[7];
  const float* sinT = (const float*)d_in[8];
  float* out = (float*)d_out;

  char* ws = (char*)d_ws;
  unsigned short* hid_bf = (unsigned short*)(ws);
  unsigned short* wq_bf = (unsigned short*)(ws + 33554432);
  unsigned short* wk_bf = (unsigned short*)(ws + 35651584);
  unsigned short* wv_bf = (unsigned short*)(ws + 37748736);
  unsigned short* wo_bf = (unsigned short*)(ws + 39845888);
  unsigned short* Qb = (unsigned short*)(ws + 41943040);
  unsigned short* Kb = (unsigned short*)(ws + 75497472);
  unsigned short* Vb = (unsigned short*)(ws + 109051904);
  unsigned short* ao_bf = (unsigned short*)(ws + 142606336);
  unsigned short* rfaK = (unsigned short*)(ws + 176160768);
  unsigned short* rfaV = (unsigned short*)(ws + 176422912);

  cvt_kernel<<<8192, 256, 0, stream>>>(hidden, hid_bf, 2097152);
  cvt_kernel<<<512, 256, 0, stream>>>(Wq, wq_bf, 131072);
  cvt_kernel<<<512, 256, 0, stream>>>(Wk, wk_bf, 131072);
  cvt_kernel<<<512, 256, 0, stream>>>(Wv, wv_bf, 131072);
  cvt_kernel<<<512, 256, 0, stream>>>(Wo, wo_bf, 131072);

  gemm_kernel<0><<<dim3(8, 128, 3), 256, 0, stream>>>(
      hid_bf, wq_bf, wk_bf, wv_bf, Qb, Kb, Vb, cosT, sinT, nullptr);

  prep_kernel<<<2048, 128, 0, stream>>>(Kb, Vb, mu, phi, rfaK, rfaV);

  attn_kernel<<<4096, 256, 0, stream>>>(Qb, Kb, Vb, rfaK, rfaV, ao_bf);

  gemm_kernel<1><<<dim3(8, 128, 1), 256, 0, stream>>>(
      ao_bf, wo_bf, nullptr, nullptr, nullptr, nullptr, nullptr, nullptr, nullptr,
      out);
}

// Round 3
// 432.692 us; speedup vs baseline: 1.4268x; 1.4268x over previous
//
#include <hip/hip_runtime.h>
#include <hip/hip_bf16.h>
#include <stdint.h>

#define SCALE_ 0.125f

typedef __bf16 bf16x8 __attribute__((ext_vector_type(8)));
typedef float f32x4 __attribute__((ext_vector_type(4)));
typedef unsigned short us8v __attribute__((ext_vector_type(8)));

__device__ __forceinline__ unsigned short f2bf(float f) {
  unsigned int u = __builtin_bit_cast(unsigned int, f);
  u += 0x7fffu + ((u >> 16) & 1u);
  return (unsigned short)(u >> 16);
}
__device__ __forceinline__ float bf2f(unsigned short h) {
  unsigned int u = ((unsigned int)h) << 16;
  return __builtin_bit_cast(float, u);
}
__device__ __forceinline__ f32x4 mfma16(bf16x8 a, bf16x8 b, f32x4 c) {
  return __builtin_amdgcn_mfma_f32_16x16x32_bf16(a, b, c, 0, 0, 0);
}
// async global->LDS, 16B per lane. LDS dest must be wave-uniform base + lane*16.
__device__ __forceinline__ void gl2lds16(const unsigned short* g, unsigned short* l) {
  __builtin_amdgcn_global_load_lds(
      (const __attribute__((address_space(1))) unsigned int*)g,
      (__attribute__((address_space(3))) unsigned int*)l, 16, 0, 0);
}

// ---------------- fp32 -> bf16 convert ----------------
__global__ __launch_bounds__(256) void cvt_kernel(const float* __restrict__ src,
                                                  unsigned short* __restrict__ dst,
                                                  int n8) {
  int i = blockIdx.x * 256 + threadIdx.x;
  if (i >= n8) return;
  us8v o;
#pragma unroll
  for (int e = 0; e < 8; ++e) o[e] = f2bf(src[(size_t)i * 8 + e]);
  *(us8v*)(dst + (size_t)i * 8) = o;
}

// ---------------- GEMM: C = A(Mx1024) @ W^T, W is (1024x1024) row-major ----------------
// m97 structure: 128x128 tile, BK=32, global_load_lds(16B) staging, 2 barriers/K-step.
template <int MODE>
__global__ __launch_bounds__(256, 2) void gemm_kernel(
    const unsigned short* __restrict__ A, const unsigned short* __restrict__ W0,
    const unsigned short* __restrict__ W1, const unsigned short* __restrict__ W2,
    unsigned short* __restrict__ Qb, unsigned short* __restrict__ Kb,
    unsigned short* __restrict__ Vb, const float* __restrict__ cosT,
    const float* __restrict__ sinT, float* __restrict__ Out) {
  __shared__ unsigned short As[128 * 32];
  __shared__ unsigned short Bs[128 * 32];
  const int tid = threadIdx.x;
  const int lane = tid & 63, wv = tid >> 6;
  const int lr = lane & 15, lg = lane >> 4;
  const int wr = wv >> 1, wc = wv & 1;
  const int tm = blockIdx.y, tn = blockIdx.x;
  const int z = blockIdx.z;
  const unsigned short* Wp = (MODE == 1) ? W0 : (z == 0 ? W0 : (z == 1 ? W1 : W2));
  const unsigned short* Ab = A + (size_t)tm * 128 * 1024;
  const unsigned short* Wb = Wp + (size_t)tn * 128 * 1024;

  const int srow = tid >> 2;        // 0..63 (round 0), +64 (round 1)
  const int scol = (tid & 3) * 8;   // 0,8,16,24 within 32-K tile

  f32x4 zero = {0.f, 0.f, 0.f, 0.f};
  f32x4 acc[4][4];
#pragma unroll
  for (int i = 0; i < 4; ++i)
#pragma unroll
    for (int j = 0; j < 4; ++j) acc[i][j] = zero;

  for (int ks = 0; ks < 32; ++ks) {
    const int k0 = ks * 32;
    __syncthreads();  // previous compute done, LDS free
    gl2lds16(Ab + (size_t)srow * 1024 + k0 + scol, As + srow * 32 + scol);
    gl2lds16(Ab + (size_t)(64 + srow) * 1024 + k0 + scol, As + (64 + srow) * 32 + scol);
    gl2lds16(Wb + (size_t)srow * 1024 + k0 + scol, Bs + srow * 32 + scol);
    gl2lds16(Wb + (size_t)(64 + srow) * 1024 + k0 + scol, Bs + (64 + srow) * 32 + scol);
    __syncthreads();  // compiler drains vmcnt before barrier; LDS ready
    bf16x8 av[4], bv[4];
#pragma unroll
    for (int mt = 0; mt < 4; ++mt)
      av[mt] = *(const bf16x8*)(As + (wr * 64 + mt * 16 + lr) * 32 + lg * 8);
#pragma unroll
    for (int nt = 0; nt < 4; ++nt)
      bv[nt] = *(const bf16x8*)(Bs + (wc * 64 + nt * 16 + lr) * 32 + lg * 8);
    __builtin_amdgcn_s_setprio(1);
#pragma unroll
    for (int mt = 0; mt < 4; ++mt)
#pragma unroll
      for (int nt = 0; nt < 4; ++nt)
        acc[mt][nt] = mfma16(av[mt], bv[nt], acc[mt][nt]);
    __builtin_amdgcn_s_setprio(0);
  }

  if constexpr (MODE == 0) {
    unsigned short* Dst = (z == 0) ? Qb : (z == 1 ? Kb : Vb);
#pragma unroll
    for (int mt = 0; mt < 4; ++mt) {
#pragma unroll
      for (int r = 0; r < 4; ++r) {
        const int m = tm * 128 + wr * 64 + mt * 16 + lg * 4 + r;
        const int b = m >> 12, s = m & 4095;
#pragma unroll
        for (int nt = 0; nt < 4; ++nt) {
          const int n = tn * 128 + wc * 64 + nt * 16 + lr;
          const int h = n >> 6, d = n & 63;
          float v = acc[mt][nt][r];
          if (z < 2) {  // RoPE
            const float cs = cosT[s * 64 + d];
            const float sn = sinT[s * 64 + d];
            const float pv = acc[mt][nt ^ 2][r];
            v = v * cs + ((nt < 2) ? -pv : pv) * sn;
          }
          Dst[((size_t)(b * 16 + h) * 4096 + s) * 64 + d] = f2bf(v);
        }
      }
    }
  } else {
#pragma unroll
    for (int mt = 0; mt < 4; ++mt) {
#pragma unroll
      for (int r = 0; r < 4; ++r) {
        const int m = tm * 128 + wr * 64 + mt * 16 + lg * 4 + r;
#pragma unroll
        for (int nt = 0; nt < 4; ++nt) {
          const int n = tn * 128 + wc * 64 + nt * 16 + lr;
          Out[(size_t)m * 1024 + n] = acc[mt][nt][r];
        }
      }
    }
  }
}

// ---------------- RFA prep: beta/gamma softmax over 128 chunk positions ----------------
__global__ __launch_bounds__(128) void prep_kernel(
    const unsigned short* __restrict__ Kb, const unsigned short* __restrict__ Vb,
    const float* __restrict__ mu, const float* __restrict__ phi,
    unsigned short* __restrict__ rfaK, unsigned short* __restrict__ rfaV) {
  __shared__ float kc[128][65];
  __shared__ float betaS[128], gammaS[128];
  __shared__ float red[8];
  const int tid = threadIdx.x, lane = tid & 63, wid = tid >> 6;
  const int bh = blockIdx.x >> 5, c = blockIdx.x & 31;
  const int h = bh & 15;
  const size_t rowbase = ((size_t)bh * 4096 + c * 128 + tid) * 64;

  float nn = 0.f, dmu = 0.f, dphi = 0.f;
#pragma unroll
  for (int d8 = 0; d8 < 8; ++d8) {
    us8v kv = *(const us8v*)(Kb + rowbase + d8 * 8);
#pragma unroll
    for (int e = 0; e < 8; ++e) {
      const int d = d8 * 8 + e;
      const float kf = bf2f(kv[e]);
      kc[tid][d] = kf;
      nn += kf * kf;
      dmu += kf * mu[h * 64 + d];
      dphi += kf * phi[h * 64 + d];
    }
  }
  const float lb = SCALE_ * dmu - 0.5f * SCALE_ * nn;
  const float lgm = SCALE_ * dphi - 0.5f * SCALE_ * nn;
  float mb = lb, mg = lgm;
  for (int off = 1; off < 64; off <<= 1) {
    mb = fmaxf(mb, __shfl_xor(mb, off));
    mg = fmaxf(mg, __shfl_xor(mg, off));
  }
  if (lane == 0) { red[wid * 2] = mb; red[wid * 2 + 1] = mg; }
  __syncthreads();
  mb = fmaxf(red[0], red[2]);
  mg = fmaxf(red[1], red[3]);
  const float eb = __expf(lb - mb), eg = __expf(lgm - mg);
  float sb = eb, sg = eg;
  for (int off = 1; off < 64; off <<= 1) {
    sb += __shfl_xor(sb, off);
    sg += __shfl_xor(sg, off);
  }
  if (lane == 0) { red[4 + wid * 2] = sb; red[4 + wid * 2 + 1] = sg; }
  betaS[tid] = eb;
  gammaS[tid] = eg;
  __syncthreads();
  sb = red[4] + red[6];
  sg = red[5] + red[7];

  if (tid < 64) {
    float a = 0.f;
    for (int j = 0; j < 128; ++j) a += betaS[j] * kc[j][tid];
    rfaK[((size_t)bh * 32 + c) * 64 + tid] = f2bf(a / sb);
  }
  __syncthreads();
#pragma unroll
  for (int d8 = 0; d8 < 8; ++d8) {
    us8v vv = *(const us8v*)(Vb + rowbase + d8 * 8);
#pragma unroll
    for (int e = 0; e < 8; ++e) kc[tid][d8 * 8 + e] = bf2f(vv[e]);
  }
  __syncthreads();
  if (tid < 64) {
    float a = 0.f;
    for (int j = 0; j < 128; ++j) a += gammaS[j] * kc[j][tid];
    rfaV[((size_t)bh * 32 + c) * 64 + tid] = f2bf(a / sg);
  }
}

// ---------------- attention tile body ----------------
// LDS layouts XOR-swizzled: Vt[d][j ^ (d&56)], Pl[row][col ^ ((row&7)<<3)].
template <int NCT, bool CH>
__device__ __forceinline__ void attn_tile(
    const unsigned short* __restrict__ ksrc, int t, int w, int qrow_w, int lr,
    int lg, int vd0, int vjb, const bf16x8* qa, f32x4* o, float* m_run,
    float* l_run, us8v* vreg, const unsigned short* __restrict__ vnext, int nnext,
    unsigned short (*__restrict__ PlW)[136], unsigned short (*__restrict__ VtP)[136]) {
  // --- QK^T (K read direct from global; V for this tile already in vreg) ---
  f32x4 st[NCT];
#pragma unroll
  for (int ct = 0; ct < NCT; ++ct) {
    bf16x8 b0 = *(const bf16x8*)(ksrc + (ct * 16 + lr) * 64 + lg * 8);
    bf16x8 b1 = *(const bf16x8*)(ksrc + (ct * 16 + lr) * 64 + 32 + lg * 8);
    f32x4 sa = {0.f, 0.f, 0.f, 0.f};
    sa = mfma16(qa[0], b0, sa);
    sa = mfma16(qa[1], b1, sa);
#pragma unroll
    for (int r = 0; r < 4; ++r) {
      float sv = sa[r] * SCALE_;
      if (!CH) {
        const int jcol = t * 128 + ct * 16 + lr;
        const int qr = qrow_w + lg * 4 + r;
        if (jcol > qr) sv = -1e30f;
      } else {
        const int cidx = ct * 16 + lr;
        if (cidx >= 4 * w) sv = -1e30f;
      }
      sa[r] = sv;
    }
    st[ct] = sa;
  }
  // --- online softmax ---
  float al[4];
#pragma unroll
  for (int r = 0; r < 4; ++r) {
    float rm = st[0][r];
#pragma unroll
    for (int ct = 1; ct < NCT; ++ct) rm = fmaxf(rm, st[ct][r]);
    rm = fmaxf(rm, __shfl_xor(rm, 1));
    rm = fmaxf(rm, __shfl_xor(rm, 2));
    rm = fmaxf(rm, __shfl_xor(rm, 4));
    rm = fmaxf(rm, __shfl_xor(rm, 8));
    const float mn = fmaxf(m_run[r], rm);
    const float a = __expf(m_run[r] - mn);
    float rs = 0.f;
#pragma unroll
    for (int ct = 0; ct < NCT; ++ct) {
      const float p = __expf(st[ct][r] - mn);
      st[ct][r] = p;
      rs += p;
    }
    rs += __shfl_xor(rs, 1);
    rs += __shfl_xor(rs, 2);
    rs += __shfl_xor(rs, 4);
    rs += __shfl_xor(rs, 8);
    l_run[r] = l_run[r] * a + rs;
    m_run[r] = mn;
    al[r] = a;
  }
#pragma unroll
  for (int dt = 0; dt < 4; ++dt)
#pragma unroll
    for (int r = 0; r < 4; ++r) o[dt][r] *= al[r];
  // P -> LDS (wave-private buffer)
#pragma unroll
  for (int ct = 0; ct < NCT; ++ct)
#pragma unroll
    for (int r = 0; r < 4; ++r) {
      const int row = lg * 4 + r;
      PlW[row][(ct * 16 + lr) ^ ((row & 7) << 3)] = f2bf(st[ct][r]);
    }
  __syncthreads();  // prev tile's PV reads of Vt are done
  // --- stage V^T from prefetched regs (swizzled scalar writes) ---
  if (!CH) {
#pragma unroll
    for (int i = 0; i < 4; ++i) {
      const int j = i * 32 + vjb;
#pragma unroll
      for (int e = 0; e < 8; ++e) VtP[vd0 + e][j ^ vd0] = vreg[i][e];
    }
  } else {
#pragma unroll
    for (int e = 0; e < 8; ++e) VtP[vd0 + e][vjb ^ vd0] = vreg[0][e];
  }
  // --- prefetch next tile's V (latency hides under this PV + next QK^T) ---
  if (nnext) {
    vreg[0] = *(const us8v*)(vnext);
    if (nnext == 4) {
#pragma unroll
      for (int i = 1; i < 4; ++i) vreg[i] = *(const us8v*)(vnext + (size_t)i * 32 * 64);
    }
  }
  __syncthreads();  // Vt ready
  // --- PV ---
  constexpr int NKS = CH ? 1 : 4;
  __builtin_amdgcn_s_setprio(1);
#pragma unroll
  for (int ks = 0; ks < NKS; ++ks) {
    bf16x8 pa = *(const bf16x8*)(&PlW[lr][(ks * 32 + lg * 8) ^ ((lr & 7) << 3)]);
#pragma unroll
    for (int dt = 0; dt < 4; ++dt) {
      const int d = dt * 16 + lr;
      bf16x8 vb = *(const bf16x8*)(&VtP[d][(ks * 32 + lg * 8) ^ (d & 56)]);
      o[dt] = mfma16(pa, vb, o[dt]);
    }
  }
  __builtin_amdgcn_s_setprio(0);
}

__global__ __launch_bounds__(256, 2) void attn_kernel(
    const unsigned short* __restrict__ Qb, const unsigned short* __restrict__ Kb,
    const unsigned short* __restrict__ Vb, const unsigned short* __restrict__ rfaK,
    const unsigned short* __restrict__ rfaV, unsigned short* __restrict__ AO) {
  __shared__ unsigned short Vt[64][136];
  __shared__ unsigned short Pl[4][16][136];
  const int tid = threadIdx.x, lane = tid & 63, wv = tid >> 6;
  const int lr = lane & 15, lg = lane >> 4;
  // XCD-aware swizzle (bijective: 4096 = 8 * 512): the 8 q-tile blocks of one
  // window (and 64 consecutive windows) land on the same XCD -> K/V L2 reuse.
  const int orig = (blockIdx.x & 7) * 512 + (blockIdx.x >> 3);
  const int qt = orig & 7, w = (orig >> 3) & 7, bh = orig >> 6;
  const size_t headbase = (size_t)bh * 4096 * 64;
  const int qrow_w = qt * 64 + wv * 16;

  bf16x8 qa[2];
  {
    const size_t qoff = headbase + (size_t)(w * 512 + qrow_w + lr) * 64;
    qa[0] = *(const bf16x8*)(Qb + qoff + lg * 8);
    qa[1] = *(const bf16x8*)(Qb + qoff + 32 + lg * 8);
  }
  f32x4 o[4];
  float m_run[4], l_run[4];
  {
    f32x4 zero = {0.f, 0.f, 0.f, 0.f};
#pragma unroll
    for (int dt = 0; dt < 4; ++dt) o[dt] = zero;
#pragma unroll
    for (int r = 0; r < 4; ++r) { m_run[r] = -INFINITY; l_run[r] = 0.f; }
  }

  const int nkt = (qt + 2) >> 1;               // window k-tiles of 128
  const int ntiles = nkt + ((w > 0) ? 1 : 0);  // + chunk tile
  const int vd0 = (tid & 7) * 8;               // d-base staged by this thread
  const int vjb = tid >> 3;                    // j index staged by this thread

  us8v vreg[4];
  {  // prefetch V for tile 0 (always a window tile)
    const unsigned short* vsrc = Vb + headbase + (size_t)(w * 512) * 64;
#pragma unroll
    for (int i = 0; i < 4; ++i)
      vreg[i] = *(const us8v*)(vsrc + (size_t)(i * 32 + vjb) * 64 + vd0);
  }

  for (int t = 0; t < ntiles; ++t) {
    const bool ischunk = (t == nkt);
    int nnext = 0;
    const unsigned short* vnext = nullptr;
    if (t + 1 < ntiles) {
      if (t + 1 == nkt) {
        nnext = 1;
        vnext = rfaV + ((size_t)bh * 32 + vjb) * 64 + vd0;
      } else {
        nnext = 4;
        vnext = Vb + headbase + (size_t)(w * 512 + (t + 1) * 128 + vjb) * 64 + vd0;
      }
    }
    if (!ischunk) {
      attn_tile<8, false>(Kb + headbase + (size_t)(w * 512 + t * 128) * 64, t, w,
                          qrow_w, lr, lg, vd0, vjb, qa, o, m_run, l_run, vreg,
                          vnext, nnext, Pl[wv], Vt);
    } else {
      attn_tile<2, true>(rfaK + (size_t)bh * 32 * 64, t, w, qrow_w, lr, lg, vd0,
                         vjb, qa, o, m_run, l_run, vreg, vnext, nnext, Pl[wv], Vt);
    }
  }
  const int b = bh >> 4, h = bh & 15;
#pragma unroll
  for (int r = 0; r < 4; ++r) {
    const float inv = 1.0f / l_run[r];
    const int s = w * 512 + qrow_w + lg * 4 + r;
#pragma unroll
    for (int dt = 0; dt < 4; ++dt) {
      AO[((size_t)(b * 4096 + s)) * 1024 + h * 64 + dt * 16 + lr] =
          f2bf(o[dt][r] * inv);
    }
  }
}

// ---------------- host launch ----------------
extern "C" void kernel_launch(void* const* d_in, const int* in_sizes, int n_in,
                              void* d_out, int out_size, void* d_ws, size_t ws_size,
                              hipStream_t stream) {
  const float* hidden = (const float*)d_in[0];
  const float* Wq = (const float*)d_in[1];
  const float* Wk = (const float*)d_in[2];
  const float* Wv = (const float*)d_in[3];
  const float* Wo = (const float*)d_in[4];
  const float* mu = (const float*)d_in[5];
  const float* phi = (const float*)d_in[6];
  const float* cosT = (const float*)d_in[7];
  const float* sinT = (const float*)d_in[8];
  float* out = (float*)d_out;

  char* ws = (char*)d_ws;
  unsigned short* hid_bf = (unsigned short*)(ws);
  unsigned short* wq_bf = (unsigned short*)(ws + 33554432);
  unsigned short* wk_bf = (unsigned short*)(ws + 35651584);
  unsigned short* wv_bf = (unsigned short*)(ws + 37748736);
  unsigned short* wo_bf = (unsigned short*)(ws + 39845888);
  unsigned short* Qb = (unsigned short*)(ws + 41943040);
  unsigned short* Kb = (unsigned short*)(ws + 75497472);
  unsigned short* Vb = (unsigned short*)(ws + 109051904);
  unsigned short* ao_bf = (unsigned short*)(ws + 142606336);
  unsigned short* rfaK = (unsigned short*)(ws + 176160768);
  unsigned short* rfaV = (unsigned short*)(ws + 176422912);

  cvt_kernel<<<8192, 256, 0, stream>>>(hidden, hid_bf, 2097152);
  cvt_kernel<<<512, 256, 0, stream>>>(Wq, wq_bf, 131072);
  cvt_kernel<<<512, 256, 0, stream>>>(Wk, wk_bf, 131072);
  cvt_kernel<<<512, 256, 0, stream>>>(Wv, wv_bf, 131072);
  cvt_kernel<<<512, 256, 0, stream>>>(Wo, wo_bf, 131072);

  gemm_kernel<0><<<dim3(8, 128, 3), 256, 0, stream>>>(
      hid_bf, wq_bf, wk_bf, wv_bf, Qb, Kb, Vb, cosT, sinT, nullptr);

  prep_kernel<<<2048, 128, 0, stream>>>(Kb, Vb, mu, phi, rfaK, rfaV);

  attn_kernel<<<4096, 256, 0, stream>>>(Qb, Kb, Vb, rfaK, rfaV, ao_bf);

  gemm_kernel<1><<<dim3(8, 128, 1), 256, 0, stream>>>(
      ao_bf, wo_bf, nullptr, nullptr, nullptr, nullptr, nullptr, nullptr, nullptr,
      out);
}

// Round 4
// 399.624 us; speedup vs baseline: 1.5449x; 1.0827x over previous
//
#include <hip/hip_runtime.h>
#include <hip/hip_bf16.h>
#include <stdint.h>

#define SCALE_ 0.125f

typedef __bf16 bf16x8 __attribute__((ext_vector_type(8)));
typedef float f32x4 __attribute__((ext_vector_type(4)));
typedef unsigned short us8v __attribute__((ext_vector_type(8)));

__device__ __forceinline__ unsigned short f2bf(float f) {
  unsigned int u = __builtin_bit_cast(unsigned int, f);
  u += 0x7fffu + ((u >> 16) & 1u);
  return (unsigned short)(u >> 16);
}
__device__ __forceinline__ float bf2f(unsigned short h) {
  unsigned int u = ((unsigned int)h) << 16;
  return __builtin_bit_cast(float, u);
}
__device__ __forceinline__ unsigned short f2bf_n(float f) {  // native cvt (RNE)
  __bf16 b = (__bf16)f;
  return __builtin_bit_cast(unsigned short, b);
}
__device__ __forceinline__ f32x4 mfma16(bf16x8 a, bf16x8 b, f32x4 c) {
  return __builtin_amdgcn_mfma_f32_16x16x32_bf16(a, b, c, 0, 0, 0);
}
// async global->LDS, 16B per lane. LDS dest must be wave-uniform base + lane*16.
__device__ __forceinline__ void gl2lds16(const unsigned short* g, unsigned short* l) {
  __builtin_amdgcn_global_load_lds(
      (const __attribute__((address_space(1))) unsigned int*)g,
      (__attribute__((address_space(3))) unsigned int*)l, 16, 0, 0);
}

// ---------------- fp32 -> bf16 convert ----------------
__global__ __launch_bounds__(256) void cvt_kernel(const float* __restrict__ src,
                                                  unsigned short* __restrict__ dst,
                                                  int n8) {
  int i = blockIdx.x * 256 + threadIdx.x;
  if (i >= n8) return;
  us8v o;
#pragma unroll
  for (int e = 0; e < 8; ++e) o[e] = f2bf(src[(size_t)i * 8 + e]);
  *(us8v*)(dst + (size_t)i * 8) = o;
}

// ---------------- GEMM: C = A(Mx1024) @ W^T, W is (1024x1024) row-major ----------------
// m97 structure: 128x128 tile, BK=32, global_load_lds(16B) staging, 2 barriers/K-step.
// XCD remap: linear block id % 8 == blockIdx.x (x fastest) == XCD. Give each XCD a
// contiguous 16-wide tm chunk (4MB of A, L2-resident) with all 8 tn per tm.
template <int MODE>
__global__ __launch_bounds__(256, 2) void gemm_kernel(
    const unsigned short* __restrict__ A, const unsigned short* __restrict__ W0,
    const unsigned short* __restrict__ W1, const unsigned short* __restrict__ W2,
    unsigned short* __restrict__ Qb, unsigned short* __restrict__ Kb,
    unsigned short* __restrict__ Vb, const float* __restrict__ cosT,
    const float* __restrict__ sinT, float* __restrict__ Out) {
  __shared__ unsigned short As[128 * 32];
  __shared__ unsigned short Bs[128 * 32];
  const int tid = threadIdx.x;
  const int lane = tid & 63, wv = tid >> 6;
  const int lr = lane & 15, lg = lane >> 4;
  const int wr = wv >> 1, wc = wv & 1;
  const int tm = blockIdx.x * 16 + (blockIdx.y >> 3);  // XCD-chunked
  const int tn = blockIdx.y & 7;
  const int z = blockIdx.z;
  const unsigned short* Wp = (MODE == 1) ? W0 : (z == 0 ? W0 : (z == 1 ? W1 : W2));
  const unsigned short* Ab = A + (size_t)tm * 128 * 1024;
  const unsigned short* Wb = Wp + (size_t)tn * 128 * 1024;

  const int srow = tid >> 2;        // 0..63 (round 0), +64 (round 1)
  const int scol = (tid & 3) * 8;   // 0,8,16,24 within 32-K tile

  f32x4 zero = {0.f, 0.f, 0.f, 0.f};
  f32x4 acc[4][4];
#pragma unroll
  for (int i = 0; i < 4; ++i)
#pragma unroll
    for (int j = 0; j < 4; ++j) acc[i][j] = zero;

  for (int ks = 0; ks < 32; ++ks) {
    const int k0 = ks * 32;
    __syncthreads();  // previous compute done, LDS free
    gl2lds16(Ab + (size_t)srow * 1024 + k0 + scol, As + srow * 32 + scol);
    gl2lds16(Ab + (size_t)(64 + srow) * 1024 + k0 + scol, As + (64 + srow) * 32 + scol);
    gl2lds16(Wb + (size_t)srow * 1024 + k0 + scol, Bs + srow * 32 + scol);
    gl2lds16(Wb + (size_t)(64 + srow) * 1024 + k0 + scol, Bs + (64 + srow) * 32 + scol);
    __syncthreads();  // compiler drains vmcnt before barrier; LDS ready
    bf16x8 av[4], bv[4];
#pragma unroll
    for (int mt = 0; mt < 4; ++mt)
      av[mt] = *(const bf16x8*)(As + (wr * 64 + mt * 16 + lr) * 32 + lg * 8);
#pragma unroll
    for (int nt = 0; nt < 4; ++nt)
      bv[nt] = *(const bf16x8*)(Bs + (wc * 64 + nt * 16 + lr) * 32 + lg * 8);
    __builtin_amdgcn_s_setprio(1);
#pragma unroll
    for (int mt = 0; mt < 4; ++mt)
#pragma unroll
      for (int nt = 0; nt < 4; ++nt)
        acc[mt][nt] = mfma16(av[mt], bv[nt], acc[mt][nt]);
    __builtin_amdgcn_s_setprio(0);
  }

  if constexpr (MODE == 0) {
    unsigned short* Dst = (z == 0) ? Qb : (z == 1 ? Kb : Vb);
#pragma unroll
    for (int mt = 0; mt < 4; ++mt) {
#pragma unroll
      for (int r = 0; r < 4; ++r) {
        const int m = tm * 128 + wr * 64 + mt * 16 + lg * 4 + r;
        const int b = m >> 12, s = m & 4095;
#pragma unroll
        for (int nt = 0; nt < 4; ++nt) {
          const int n = tn * 128 + wc * 64 + nt * 16 + lr;
          const int h = n >> 6, d = n & 63;
          float v = acc[mt][nt][r];
          if (z < 2) {  // RoPE
            const float cs = cosT[s * 64 + d];
            const float sn = sinT[s * 64 + d];
            const float pv = acc[mt][nt ^ 2][r];
            v = v * cs + ((nt < 2) ? -pv : pv) * sn;
          }
          Dst[((size_t)(b * 16 + h) * 4096 + s) * 64 + d] = f2bf_n(v);
        }
      }
    }
  } else {
#pragma unroll
    for (int mt = 0; mt < 4; ++mt) {
#pragma unroll
      for (int r = 0; r < 4; ++r) {
        const int m = tm * 128 + wr * 64 + mt * 16 + lg * 4 + r;
#pragma unroll
        for (int nt = 0; nt < 4; ++nt) {
          const int n = tn * 128 + wc * 64 + nt * 16 + lr;
          Out[(size_t)m * 1024 + n] = acc[mt][nt][r];
        }
      }
    }
  }
}

// ---------------- RFA prep: beta/gamma softmax over 128 chunk positions ----------------
__global__ __launch_bounds__(128) void prep_kernel(
    const unsigned short* __restrict__ Kb, const unsigned short* __restrict__ Vb,
    const float* __restrict__ mu, const float* __restrict__ phi,
    unsigned short* __restrict__ rfaK, unsigned short* __restrict__ rfaV) {
  __shared__ float kc[128][65];
  __shared__ float betaS[128], gammaS[128];
  __shared__ float red[8];
  const int tid = threadIdx.x, lane = tid & 63, wid = tid >> 6;
  const int bh = blockIdx.x >> 5, c = blockIdx.x & 31;
  const int h = bh & 15;
  const size_t rowbase = ((size_t)bh * 4096 + c * 128 + tid) * 64;

  float nn = 0.f, dmu = 0.f, dphi = 0.f;
#pragma unroll
  for (int d8 = 0; d8 < 8; ++d8) {
    us8v kv = *(const us8v*)(Kb + rowbase + d8 * 8);
#pragma unroll
    for (int e = 0; e < 8; ++e) {
      const int d = d8 * 8 + e;
      const float kf = bf2f(kv[e]);
      kc[tid][d] = kf;
      nn += kf * kf;
      dmu += kf * mu[h * 64 + d];
      dphi += kf * phi[h * 64 + d];
    }
  }
  const float lb = SCALE_ * dmu - 0.5f * SCALE_ * nn;
  const float lgm = SCALE_ * dphi - 0.5f * SCALE_ * nn;
  float mb = lb, mg = lgm;
  for (int off = 1; off < 64; off <<= 1) {
    mb = fmaxf(mb, __shfl_xor(mb, off));
    mg = fmaxf(mg, __shfl_xor(mg, off));
  }
  if (lane == 0) { red[wid * 2] = mb; red[wid * 2 + 1] = mg; }
  __syncthreads();
  mb = fmaxf(red[0], red[2]);
  mg = fmaxf(red[1], red[3]);
  const float eb = __expf(lb - mb), eg = __expf(lgm - mg);
  float sb = eb, sg = eg;
  for (int off = 1; off < 64; off <<= 1) {
    sb += __shfl_xor(sb, off);
    sg += __shfl_xor(sg, off);
  }
  if (lane == 0) { red[4 + wid * 2] = sb; red[4 + wid * 2 + 1] = sg; }
  betaS[tid] = eb;
  gammaS[tid] = eg;
  __syncthreads();
  sb = red[4] + red[6];
  sg = red[5] + red[7];

  if (tid < 64) {
    float a = 0.f;
    for (int j = 0; j < 128; ++j) a += betaS[j] * kc[j][tid];
    rfaK[((size_t)bh * 32 + c) * 64 + tid] = f2bf(a / sb);
  }
  __syncthreads();
#pragma unroll
  for (int d8 = 0; d8 < 8; ++d8) {
    us8v vv = *(const us8v*)(Vb + rowbase + d8 * 8);
#pragma unroll
    for (int e = 0; e < 8; ++e) kc[tid][d8 * 8 + e] = bf2f(vv[e]);
  }
  __syncthreads();
  if (tid < 64) {
    float a = 0.f;
    for (int j = 0; j < 128; ++j) a += gammaS[j] * kc[j][tid];
    rfaV[((size_t)bh * 32 + c) * 64 + tid] = f2bf(a / sg);
  }
}

// ---------------- attention tile body ----------------
// LDS layouts XOR-swizzled: Vt[d][j ^ (d&56)], Pl[row][col ^ ((row&7)<<3)].
// ONE barrier per tile: V for this tile staged at tile start into the
// double-buffered VtP; barrier before PV orders all waves' stage/PV pairs.
// MASK: causal masking applies only to the diagonal tile (t == nkt-1).
template <int NCT, bool CH, bool MASK>
__device__ __forceinline__ void attn_tile(
    const unsigned short* __restrict__ ksrc, int t, int w, int qrow_w, int lr,
    int lg, int vd0, int vjb, const bf16x8* qa, f32x4* o, float* m_run,
    float* l_run, us8v* vreg, const unsigned short* __restrict__ vnext, int nnext,
    unsigned short (*__restrict__ PlW)[136], unsigned short (*__restrict__ VtP)[136]) {
  // --- stage this tile's V^T from prefetched regs (overlaps QK^T below) ---
  if (!CH) {
#pragma unroll
    for (int i = 0; i < 4; ++i) {
      const int j = i * 32 + vjb;
#pragma unroll
      for (int e = 0; e < 8; ++e) VtP[vd0 + e][j ^ vd0] = vreg[i][e];
    }
  } else {
#pragma unroll
    for (int e = 0; e < 8; ++e) VtP[vd0 + e][vjb ^ vd0] = vreg[0][e];
  }
  // --- QK^T (K read direct from global / L2) ---
  f32x4 st[NCT];
#pragma unroll
  for (int ct = 0; ct < NCT; ++ct) {
    bf16x8 b0 = *(const bf16x8*)(ksrc + (ct * 16 + lr) * 64 + lg * 8);
    bf16x8 b1 = *(const bf16x8*)(ksrc + (ct * 16 + lr) * 64 + 32 + lg * 8);
    f32x4 sa = {0.f, 0.f, 0.f, 0.f};
    sa = mfma16(qa[0], b0, sa);
    sa = mfma16(qa[1], b1, sa);
#pragma unroll
    for (int r = 0; r < 4; ++r) {
      float sv = sa[r] * SCALE_;
      if constexpr (CH) {
        const int cidx = ct * 16 + lr;
        if (cidx >= 4 * w) sv = -1e30f;
      } else if constexpr (MASK) {
        const int jcol = t * 128 + ct * 16 + lr;
        const int qr = qrow_w + lg * 4 + r;
        if (jcol > qr) sv = -1e30f;
      }
      sa[r] = sv;
    }
    st[ct] = sa;
  }
  // --- prefetch next tile's V (hides under softmax + PV) ---
  if (nnext) {
    vreg[0] = *(const us8v*)(vnext);
    if (nnext == 4) {
#pragma unroll
      for (int i = 1; i < 4; ++i) vreg[i] = *(const us8v*)(vnext + (size_t)i * 32 * 64);
    }
  }
  // --- online softmax ---
  float al[4];
#pragma unroll
  for (int r = 0; r < 4; ++r) {
    float rm = st[0][r];
#pragma unroll
    for (int ct = 1; ct < NCT; ++ct) rm = fmaxf(rm, st[ct][r]);
    rm = fmaxf(rm, __shfl_xor(rm, 1));
    rm = fmaxf(rm, __shfl_xor(rm, 2));
    rm = fmaxf(rm, __shfl_xor(rm, 4));
    rm = fmaxf(rm, __shfl_xor(rm, 8));
    const float mn = fmaxf(m_run[r], rm);
    const float a = __expf(m_run[r] - mn);
    float rs = 0.f;
#pragma unroll
    for (int ct = 0; ct < NCT; ++ct) {
      const float p = __expf(st[ct][r] - mn);
      st[ct][r] = p;
      rs += p;
    }
    rs += __shfl_xor(rs, 1);
    rs += __shfl_xor(rs, 2);
    rs += __shfl_xor(rs, 4);
    rs += __shfl_xor(rs, 8);
    l_run[r] = l_run[r] * a + rs;
    m_run[r] = mn;
    al[r] = a;
  }
#pragma unroll
  for (int dt = 0; dt < 4; ++dt)
#pragma unroll
    for (int r = 0; r < 4; ++r) o[dt][r] *= al[r];
  // P -> LDS (wave-private buffer; native RNE cvt)
#pragma unroll
  for (int ct = 0; ct < NCT; ++ct)
#pragma unroll
    for (int r = 0; r < 4; ++r) {
      const int row = lg * 4 + r;
      PlW[row][(ct * 16 + lr) ^ ((row & 7) << 3)] = f2bf_n(st[ct][r]);
    }
  __syncthreads();  // Vt[t&1] staged by all waves; prev-buffer readers done
  // --- PV ---
  constexpr int NKS = CH ? 1 : 4;
  __builtin_amdgcn_s_setprio(1);
#pragma unroll
  for (int ks = 0; ks < NKS; ++ks) {
    bf16x8 pa = *(const bf16x8*)(&PlW[lr][(ks * 32 + lg * 8) ^ ((lr & 7) << 3)]);
#pragma unroll
    for (int dt = 0; dt < 4; ++dt) {
      const int d = dt * 16 + lr;
      bf16x8 vb = *(const bf16x8*)(&VtP[d][(ks * 32 + lg * 8) ^ (d & 56)]);
      o[dt] = mfma16(pa, vb, o[dt]);
    }
  }
  __builtin_amdgcn_s_setprio(0);
}

__global__ __launch_bounds__(256, 2) void attn_kernel(
    const unsigned short* __restrict__ Qb, const unsigned short* __restrict__ Kb,
    const unsigned short* __restrict__ Vb, const unsigned short* __restrict__ rfaK,
    const unsigned short* __restrict__ rfaV, unsigned short* __restrict__ AO) {
  __shared__ unsigned short Vt[2][64][136];  // double-buffered -> 1 barrier/tile
  __shared__ unsigned short Pl[4][16][136];
  const int tid = threadIdx.x, lane = tid & 63, wv = tid >> 6;
  const int lr = lane & 15, lg = lane >> 4;
  // XCD-aware swizzle (bijective: 4096 = 8 * 512)
  const int orig = (blockIdx.x & 7) * 512 + (blockIdx.x >> 3);
  const int qt = orig & 7, w = (orig >> 3) & 7, bh = orig >> 6;
  const size_t headbase = (size_t)bh * 4096 * 64;
  const int qrow_w = qt * 64 + wv * 16;

  bf16x8 qa[2];
  {
    const size_t qoff = headbase + (size_t)(w * 512 + qrow_w + lr) * 64;
    qa[0] = *(const bf16x8*)(Qb + qoff + lg * 8);
    qa[1] = *(const bf16x8*)(Qb + qoff + 32 + lg * 8);
  }
  f32x4 o[4];
  float m_run[4], l_run[4];
  {
    f32x4 zero = {0.f, 0.f, 0.f, 0.f};
#pragma unroll
    for (int dt = 0; dt < 4; ++dt) o[dt] = zero;
#pragma unroll
    for (int r = 0; r < 4; ++r) { m_run[r] = -INFINITY; l_run[r] = 0.f; }
  }

  const int nkt = (qt + 2) >> 1;               // window k-tiles of 128
  const int ntiles = nkt + ((w > 0) ? 1 : 0);  // + chunk tile
  const int vd0 = (tid & 7) * 8;               // d-base staged by this thread
  const int vjb = tid >> 3;                    // j index staged by this thread

  us8v vreg[4];
  {  // prefetch V for tile 0 (always a window tile)
    const unsigned short* vsrc = Vb + headbase + (size_t)(w * 512) * 64;
#pragma unroll
    for (int i = 0; i < 4; ++i)
      vreg[i] = *(const us8v*)(vsrc + (size_t)(i * 32 + vjb) * 64 + vd0);
  }

  for (int t = 0; t < ntiles; ++t) {
    const bool ischunk = (t == nkt);
    int nnext = 0;
    const unsigned short* vnext = nullptr;
    if (t + 1 < ntiles) {
      if (t + 1 == nkt) {
        nnext = 1;
        vnext = rfaV + ((size_t)bh * 32 + vjb) * 64 + vd0;
      } else {
        nnext = 4;
        vnext = Vb + headbase + (size_t)(w * 512 + (t + 1) * 128 + vjb) * 64 + vd0;
      }
    }
    unsigned short (*vtp)[136] = Vt[t & 1];
    if (!ischunk) {
      const unsigned short* ksrc = Kb + headbase + (size_t)(w * 512 + t * 128) * 64;
      if (t == nkt - 1) {
        attn_tile<8, false, true>(ksrc, t, w, qrow_w, lr, lg, vd0, vjb, qa, o,
                                  m_run, l_run, vreg, vnext, nnext, Pl[wv], vtp);
      } else {
        attn_tile<8, false, false>(ksrc, t, w, qrow_w, lr, lg, vd0, vjb, qa, o,
                                   m_run, l_run, vreg, vnext, nnext, Pl[wv], vtp);
      }
    } else {
      attn_tile<2, true, true>(rfaK + (size_t)bh * 32 * 64, t, w, qrow_w, lr, lg,
                               vd0, vjb, qa, o, m_run, l_run, vreg, vnext, nnext,
                               Pl[wv], vtp);
    }
  }
  const int b = bh >> 4, h = bh & 15;
#pragma unroll
  for (int r = 0; r < 4; ++r) {
    const float inv = 1.0f / l_run[r];
    const int s = w * 512 + qrow_w + lg * 4 + r;
#pragma unroll
    for (int dt = 0; dt < 4; ++dt) {
      AO[((size_t)(b * 4096 + s)) * 1024 + h * 64 + dt * 16 + lr] =
          f2bf_n(o[dt][r] * inv);
    }
  }
}

// ---------------- host launch ----------------
extern "C" void kernel_launch(void* const* d_in, const int* in_sizes, int n_in,
                              void* d_out, int out_size, void* d_ws, size_t ws_size,
                              hipStream_t stream) {
  const float* hidden = (const float*)d_in[0];
  const float* Wq = (const float*)d_in[1];
  const float* Wk = (const float*)d_in[2];
  const float* Wv = (const float*)d_in[3];
  const float* Wo = (const float*)d_in[4];
  const float* mu = (const float*)d_in[5];
  const float* phi = (const float*)d_in[6];
  const float* cosT = (const float*)d_in[7];
  const float* sinT = (const float*)d_in[8];
  float* out = (float*)d_out;

  char* ws = (char*)d_ws;
  unsigned short* hid_bf = (unsigned short*)(ws);
  unsigned short* wq_bf = (unsigned short*)(ws + 33554432);
  unsigned short* wk_bf = (unsigned short*)(ws + 35651584);
  unsigned short* wv_bf = (unsigned short*)(ws + 37748736);
  unsigned short* wo_bf = (unsigned short*)(ws + 39845888);
  unsigned short* Qb = (unsigned short*)(ws + 41943040);
  unsigned short* Kb = (unsigned short*)(ws + 75497472);
  unsigned short* Vb = (unsigned short*)(ws + 109051904);
  unsigned short* ao_bf = (unsigned short*)(ws + 142606336);
  unsigned short* rfaK = (unsigned short*)(ws + 176160768);
  unsigned short* rfaV = (unsigned short*)(ws + 176422912);

  cvt_kernel<<<8192, 256, 0, stream>>>(hidden, hid_bf, 2097152);
  cvt_kernel<<<512, 256, 0, stream>>>(Wq, wq_bf, 131072);
  cvt_kernel<<<512, 256, 0, stream>>>(Wk, wk_bf, 131072);
  cvt_kernel<<<512, 256, 0, stream>>>(Wv, wv_bf, 131072);
  cvt_kernel<<<512, 256, 0, stream>>>(Wo, wo_bf, 131072);

  gemm_kernel<0><<<dim3(8, 128, 3), 256, 0, stream>>>(
      hid_bf, wq_bf, wk_bf, wv_bf, Qb, Kb, Vb, cosT, sinT, nullptr);

  prep_kernel<<<2048, 128, 0, stream>>>(Kb, Vb, mu, phi, rfaK, rfaV);

  attn_kernel<<<4096, 256, 0, stream>>>(Qb, Kb, Vb, rfaK, rfaV, ao_bf);

  gemm_kernel<1><<<dim3(8, 128, 1), 256, 0, stream>>>(
      ao_bf, wo_bf, nullptr, nullptr, nullptr, nullptr, nullptr, nullptr, nullptr,
      out);
}